// Round 4
// baseline (557.652 us; speedup 1.0000x reference)
//
#include <hip/hip_runtime.h>

// SNN elementwise state update. Memory-bound: 5 reads + 5 writes of 64 MiB fp32
// = 671 MB traffic -> ~107 us floor at the 6.29 TB/s measured D2D-copy ceiling.
// CFG: dt=0.5, kappa_j=0.2, tau_j=8.0, gamma_m=0.1, R_m=5.0, tau_m=10.0,
//      thresh=1.0, t_ref=2.0, tau_tr=20.0
//
// History: 118 us one-shot float4 -> 115 us (grid-stride 2048 blocks + NT
// loads/stores). This version: unroll 2x inside the grid-stride loop
// (two consecutive float4 per stream per iteration) -> 10 outstanding NT
// loads per wave instead of 5, half the loop overhead.

typedef float f32x4 __attribute__((ext_vector_type(4)));

struct Out5 { float v, s, x, j, r; };

__device__ __forceinline__ Out5 snn_step(float I, float v, float x, float j, float r) {
#pragma clang fp contract(off)
    // refractory countdown
    float rc = fmaxf(r - 0.5f, 0.0f);
    // synaptic current: j += (dt/tau_j) * (-kappa_j*j + I); dt/tau_j = 0.0625 exact
    float jn = j + 0.0625f * (-0.2f * j + I);
    // membrane potential, frozen while refractory
    float isr = (rc > 0.0f) ? 1.0f : 0.0f;
    float vn = v + ((1.0f - isr) * 0.05f) * ((-0.1f) * v + 5.0f * jn);
    // threshold -> spike, reset
    float sp = (vn > 1.0f) ? 1.0f : 0.0f;
    Out5 o;
    o.v = vn * (1.0f - sp);
    o.s = sp;
    // low-pass spike trace: x - x/tau_tr + spikes (true division to match ref rounding)
    o.x = x - x / 20.0f + sp;
    o.j = jn;
    o.r = (sp > 0.0f) ? 2.0f : rc;
    return o;
}

__global__ __launch_bounds__(256) void bPC_SNNLayer_65274912965275_kernel(
    const f32x4* __restrict__ Ic,
    const f32x4* __restrict__ v_in,
    const f32x4* __restrict__ x_in,
    const f32x4* __restrict__ j_in,
    const f32x4* __restrict__ r_in,
    f32x4* __restrict__ v_out,
    f32x4* __restrict__ s_out,
    f32x4* __restrict__ x_out,
    f32x4* __restrict__ j_out,
    f32x4* __restrict__ r_out,
    int n8) {  // number of float4-PAIRS (n4/2)
#pragma clang fp contract(off)
    const int stride = gridDim.x * blockDim.x;
    for (int p = blockIdx.x * blockDim.x + threadIdx.x; p < n8; p += stride) {
        const int idx = 2 * p;
        // Issue all 10 loads before any compute: 10 outstanding NT loads/wave.
        f32x4 I0 = __builtin_nontemporal_load(&Ic[idx]);
        f32x4 I1 = __builtin_nontemporal_load(&Ic[idx + 1]);
        f32x4 v0 = __builtin_nontemporal_load(&v_in[idx]);
        f32x4 v1 = __builtin_nontemporal_load(&v_in[idx + 1]);
        f32x4 x0 = __builtin_nontemporal_load(&x_in[idx]);
        f32x4 x1 = __builtin_nontemporal_load(&x_in[idx + 1]);
        f32x4 j0 = __builtin_nontemporal_load(&j_in[idx]);
        f32x4 j1 = __builtin_nontemporal_load(&j_in[idx + 1]);
        f32x4 r0 = __builtin_nontemporal_load(&r_in[idx]);
        f32x4 r1 = __builtin_nontemporal_load(&r_in[idx + 1]);

        f32x4 vo0, so0, xo0, jo0, ro0;
        f32x4 vo1, so1, xo1, jo1, ro1;
#pragma unroll
        for (int k = 0; k < 4; ++k) {
            Out5 a = snn_step(I0[k], v0[k], x0[k], j0[k], r0[k]);
            vo0[k] = a.v; so0[k] = a.s; xo0[k] = a.x; jo0[k] = a.j; ro0[k] = a.r;
            Out5 b = snn_step(I1[k], v1[k], x1[k], j1[k], r1[k]);
            vo1[k] = b.v; so1[k] = b.s; xo1[k] = b.x; jo1[k] = b.j; ro1[k] = b.r;
        }

        __builtin_nontemporal_store(vo0, &v_out[idx]);
        __builtin_nontemporal_store(vo1, &v_out[idx + 1]);
        __builtin_nontemporal_store(so0, &s_out[idx]);
        __builtin_nontemporal_store(so1, &s_out[idx + 1]);
        __builtin_nontemporal_store(xo0, &x_out[idx]);
        __builtin_nontemporal_store(xo1, &x_out[idx + 1]);
        __builtin_nontemporal_store(jo0, &j_out[idx]);
        __builtin_nontemporal_store(jo1, &j_out[idx + 1]);
        __builtin_nontemporal_store(ro0, &r_out[idx]);
        __builtin_nontemporal_store(ro1, &r_out[idx + 1]);
    }
}

extern "C" void kernel_launch(void* const* d_in, const int* in_sizes, int n_in,
                              void* d_out, int out_size, void* d_ws, size_t ws_size,
                              hipStream_t stream) {
    // setup_inputs order: total_input_current, v, x, j, ref_count
    const float* I = (const float*)d_in[0];
    const float* v = (const float*)d_in[1];
    const float* x = (const float*)d_in[2];
    const float* j = (const float*)d_in[3];
    const float* r = (const float*)d_in[4];

    const int n = in_sizes[0];       // 4096*4096 = 16777216, divisible by 8
    const int n8 = n / 8;            // float4-pairs

    float* out = (float*)d_out;      // (v, s, x, j, ref_count) concatenated
    float* vo = out;
    float* so = out + (size_t)n;
    float* xo = out + 2 * (size_t)n;
    float* jo = out + 3 * (size_t)n;
    float* ro = out + 4 * (size_t)n;

    const int block = 256;
    // G11: memory-bound -> cap grid (~8 blocks/CU, 256 CU) and grid-stride.
    int grid = (n8 + block - 1) / block;
    if (grid > 2048) grid = 2048;
    bPC_SNNLayer_65274912965275_kernel<<<grid, block, 0, stream>>>(
        (const f32x4*)I, (const f32x4*)v, (const f32x4*)x,
        (const f32x4*)j, (const f32x4*)r,
        (f32x4*)vo, (f32x4*)so, (f32x4*)xo, (f32x4*)jo, (f32x4*)ro, n8);
}

// Round 5
// 536.369 us; speedup vs baseline: 1.0397x; 1.0397x over previous
//
#include <hip/hip_runtime.h>

// SNN elementwise state update. Memory-bound: 5 reads + 5 writes of 64 MiB fp32
// = 671 MB traffic -> ~107 us floor at the 6.29 TB/s measured D2D-copy ceiling.
// CFG: dt=0.5, kappa_j=0.2, tau_j=8.0, gamma_m=0.1, R_m=5.0, tau_m=10.0,
//      thresh=1.0, t_ref=2.0, tau_tr=20.0
//
// History:
//   118 us  one-shot float4
//   115 us  grid-stride 2048 blocks + NT loads/stores (R3, dur 532.4)
//   140 us  REGRESSED: 2x unroll w/ consecutive-pairs (idx=2p) broke
//           per-instruction coalescing (lane stride 32B) (R4, dur 557.7)
// This version: 2x unroll with BLOCK-STRIDED pairs (i0, i0+gridStride):
// every load/store instruction keeps lane-contiguous addresses while the
// wave still has 10 NT loads in flight.

typedef float f32x4 __attribute__((ext_vector_type(4)));

struct Out5 { float v, s, x, j, r; };

__device__ __forceinline__ Out5 snn_step(float I, float v, float x, float j, float r) {
#pragma clang fp contract(off)
    // refractory countdown
    float rc = fmaxf(r - 0.5f, 0.0f);
    // synaptic current: j += (dt/tau_j) * (-kappa_j*j + I); dt/tau_j = 0.0625 exact
    float jn = j + 0.0625f * (-0.2f * j + I);
    // membrane potential, frozen while refractory
    float isr = (rc > 0.0f) ? 1.0f : 0.0f;
    float vn = v + ((1.0f - isr) * 0.05f) * ((-0.1f) * v + 5.0f * jn);
    // threshold -> spike, reset
    float sp = (vn > 1.0f) ? 1.0f : 0.0f;
    Out5 o;
    o.v = vn * (1.0f - sp);
    o.s = sp;
    // low-pass spike trace: x - x/tau_tr + spikes (true division to match ref rounding)
    o.x = x - x / 20.0f + sp;
    o.j = jn;
    o.r = (sp > 0.0f) ? 2.0f : rc;
    return o;
}

__global__ __launch_bounds__(256) void bPC_SNNLayer_65274912965275_kernel(
    const f32x4* __restrict__ Ic,
    const f32x4* __restrict__ v_in,
    const f32x4* __restrict__ x_in,
    const f32x4* __restrict__ j_in,
    const f32x4* __restrict__ r_in,
    f32x4* __restrict__ v_out,
    f32x4* __restrict__ s_out,
    f32x4* __restrict__ x_out,
    f32x4* __restrict__ j_out,
    f32x4* __restrict__ r_out,
    int n4) {
#pragma clang fp contract(off)
    const int gstride = gridDim.x * blockDim.x;
    for (int i0 = blockIdx.x * blockDim.x + threadIdx.x; i0 < n4; i0 += 2 * gstride) {
        const int i1 = i0 + gstride;
        const bool has1 = (i1 < n4);

        // Issue all loads before compute; both i0 and i1 accesses are
        // lane-contiguous per instruction.
        f32x4 I0 = __builtin_nontemporal_load(&Ic[i0]);
        f32x4 v0 = __builtin_nontemporal_load(&v_in[i0]);
        f32x4 x0 = __builtin_nontemporal_load(&x_in[i0]);
        f32x4 j0 = __builtin_nontemporal_load(&j_in[i0]);
        f32x4 r0 = __builtin_nontemporal_load(&r_in[i0]);
        f32x4 I1 = {}, v1 = {}, x1 = {}, j1 = {}, r1 = {};
        if (has1) {
            I1 = __builtin_nontemporal_load(&Ic[i1]);
            v1 = __builtin_nontemporal_load(&v_in[i1]);
            x1 = __builtin_nontemporal_load(&x_in[i1]);
            j1 = __builtin_nontemporal_load(&j_in[i1]);
            r1 = __builtin_nontemporal_load(&r_in[i1]);
        }

        f32x4 vo0, so0, xo0, jo0, ro0;
        f32x4 vo1, so1, xo1, jo1, ro1;
#pragma unroll
        for (int k = 0; k < 4; ++k) {
            Out5 a = snn_step(I0[k], v0[k], x0[k], j0[k], r0[k]);
            vo0[k] = a.v; so0[k] = a.s; xo0[k] = a.x; jo0[k] = a.j; ro0[k] = a.r;
            Out5 b = snn_step(I1[k], v1[k], x1[k], j1[k], r1[k]);
            vo1[k] = b.v; so1[k] = b.s; xo1[k] = b.x; jo1[k] = b.j; ro1[k] = b.r;
        }

        __builtin_nontemporal_store(vo0, &v_out[i0]);
        __builtin_nontemporal_store(so0, &s_out[i0]);
        __builtin_nontemporal_store(xo0, &x_out[i0]);
        __builtin_nontemporal_store(jo0, &j_out[i0]);
        __builtin_nontemporal_store(ro0, &r_out[i0]);
        if (has1) {
            __builtin_nontemporal_store(vo1, &v_out[i1]);
            __builtin_nontemporal_store(so1, &s_out[i1]);
            __builtin_nontemporal_store(xo1, &x_out[i1]);
            __builtin_nontemporal_store(jo1, &j_out[i1]);
            __builtin_nontemporal_store(ro1, &r_out[i1]);
        }
    }
}

extern "C" void kernel_launch(void* const* d_in, const int* in_sizes, int n_in,
                              void* d_out, int out_size, void* d_ws, size_t ws_size,
                              hipStream_t stream) {
    // setup_inputs order: total_input_current, v, x, j, ref_count
    const float* I = (const float*)d_in[0];
    const float* v = (const float*)d_in[1];
    const float* x = (const float*)d_in[2];
    const float* j = (const float*)d_in[3];
    const float* r = (const float*)d_in[4];

    const int n = in_sizes[0];       // 4096*4096 = 16777216, divisible by 4
    const int n4 = n / 4;

    float* out = (float*)d_out;      // (v, s, x, j, ref_count) concatenated
    float* vo = out;
    float* so = out + (size_t)n;
    float* xo = out + 2 * (size_t)n;
    float* jo = out + 3 * (size_t)n;
    float* ro = out + 4 * (size_t)n;

    const int block = 256;
    // G11: memory-bound -> cap grid (~8 blocks/CU, 256 CU) and grid-stride.
    int grid = (n4 + block - 1) / block;
    if (grid > 2048) grid = 2048;
    bPC_SNNLayer_65274912965275_kernel<<<grid, block, 0, stream>>>(
        (const f32x4*)I, (const f32x4*)v, (const f32x4*)x,
        (const f32x4*)j, (const f32x4*)r,
        (f32x4*)vo, (f32x4*)so, (f32x4*)xo, (f32x4*)jo, (f32x4*)ro, n4);
}

// Round 6
// 530.861 us; speedup vs baseline: 1.0505x; 1.0104x over previous
//
#include <hip/hip_runtime.h>

// SNN elementwise state update. Memory-bound: 5 reads + 5 writes of 64 MiB fp32
// = 671 MB traffic -> ~107 us floor at the 6.29 TB/s measured D2D-copy ceiling.
// CFG: dt=0.5, kappa_j=0.2, tau_j=8.0, gamma_m=0.1, R_m=5.0, tau_m=10.0,
//      thresh=1.0, t_ref=2.0, tau_tr=20.0
//
// History (kernel-side us; dur_us includes ~420 us of harness fills):
//   118 us  one-shot float4 (dur 540.2)
//   115 us  grid-stride 2048 blocks + NT loads/stores (R3, dur 532.4)  <= BEST
//   140 us  2x unroll consecutive-pairs: broke coalescing (R4, dur 557.7)
//   119 us  2x unroll block-strided pairs: neutral/worse (R5, dur 536.4)
// Conclusion: TLP (8 waves/SIMD, 2048 blocks) already saturates HBM; extra
// per-wave MLP doesn't help. This is R3 restored — ~93% of the measured
// read+write copy ceiling.

typedef float f32x4 __attribute__((ext_vector_type(4)));

struct Out5 { float v, s, x, j, r; };

__device__ __forceinline__ Out5 snn_step(float I, float v, float x, float j, float r) {
#pragma clang fp contract(off)
    // refractory countdown
    float rc = fmaxf(r - 0.5f, 0.0f);
    // synaptic current: j += (dt/tau_j) * (-kappa_j*j + I); dt/tau_j = 0.0625 exact
    float jn = j + 0.0625f * (-0.2f * j + I);
    // membrane potential, frozen while refractory
    float isr = (rc > 0.0f) ? 1.0f : 0.0f;
    float vn = v + ((1.0f - isr) * 0.05f) * ((-0.1f) * v + 5.0f * jn);
    // threshold -> spike, reset
    float sp = (vn > 1.0f) ? 1.0f : 0.0f;
    Out5 o;
    o.v = vn * (1.0f - sp);
    o.s = sp;
    // low-pass spike trace: x - x/tau_tr + spikes (true division to match ref rounding)
    o.x = x - x / 20.0f + sp;
    o.j = jn;
    o.r = (sp > 0.0f) ? 2.0f : rc;
    return o;
}

__global__ __launch_bounds__(256) void bPC_SNNLayer_65274912965275_kernel(
    const f32x4* __restrict__ Ic,
    const f32x4* __restrict__ v_in,
    const f32x4* __restrict__ x_in,
    const f32x4* __restrict__ j_in,
    const f32x4* __restrict__ r_in,
    f32x4* __restrict__ v_out,
    f32x4* __restrict__ s_out,
    f32x4* __restrict__ x_out,
    f32x4* __restrict__ j_out,
    f32x4* __restrict__ r_out,
    int n4) {
#pragma clang fp contract(off)
    const int stride = gridDim.x * blockDim.x;
    for (int idx = blockIdx.x * blockDim.x + threadIdx.x; idx < n4; idx += stride) {
        f32x4 I = __builtin_nontemporal_load(&Ic[idx]);
        f32x4 v = __builtin_nontemporal_load(&v_in[idx]);
        f32x4 x = __builtin_nontemporal_load(&x_in[idx]);
        f32x4 j = __builtin_nontemporal_load(&j_in[idx]);
        f32x4 r = __builtin_nontemporal_load(&r_in[idx]);

        f32x4 vo, so, xo, jo, ro;
#pragma unroll
        for (int k = 0; k < 4; ++k) {
            Out5 o = snn_step(I[k], v[k], x[k], j[k], r[k]);
            vo[k] = o.v;
            so[k] = o.s;
            xo[k] = o.x;
            jo[k] = o.j;
            ro[k] = o.r;
        }

        __builtin_nontemporal_store(vo, &v_out[idx]);
        __builtin_nontemporal_store(so, &s_out[idx]);
        __builtin_nontemporal_store(xo, &x_out[idx]);
        __builtin_nontemporal_store(jo, &j_out[idx]);
        __builtin_nontemporal_store(ro, &r_out[idx]);
    }
}

extern "C" void kernel_launch(void* const* d_in, const int* in_sizes, int n_in,
                              void* d_out, int out_size, void* d_ws, size_t ws_size,
                              hipStream_t stream) {
    // setup_inputs order: total_input_current, v, x, j, ref_count
    const float* I = (const float*)d_in[0];
    const float* v = (const float*)d_in[1];
    const float* x = (const float*)d_in[2];
    const float* j = (const float*)d_in[3];
    const float* r = (const float*)d_in[4];

    const int n = in_sizes[0];       // 4096*4096 = 16777216, divisible by 4
    const int n4 = n / 4;

    float* out = (float*)d_out;      // (v, s, x, j, ref_count) concatenated
    float* vo = out;
    float* so = out + (size_t)n;
    float* xo = out + 2 * (size_t)n;
    float* jo = out + 3 * (size_t)n;
    float* ro = out + 4 * (size_t)n;

    const int block = 256;
    // G11: memory-bound -> cap grid at ~8 blocks/CU (256 CU) and grid-stride.
    int grid = (n4 + block - 1) / block;
    if (grid > 2048) grid = 2048;
    bPC_SNNLayer_65274912965275_kernel<<<grid, block, 0, stream>>>(
        (const f32x4*)I, (const f32x4*)v, (const f32x4*)x,
        (const f32x4*)j, (const f32x4*)r,
        (f32x4*)vo, (f32x4*)so, (f32x4*)xo, (f32x4*)jo, (f32x4*)ro, n4);
}